// Round 5
// baseline (206.871 us; speedup 1.0000x reference)
//
#include <hip/hip_runtime.h>
#include <stdint.h>

// ---------------------------------------------------------------------------
// BinaryLinear: out[M,N] = x[M,K] @ sign(W[N,K])^T + bias[N]
// M=8192, K=2048, N=2048, fp32 in/out.
// Round 5: (1) single merged prep kernel (cvt_x + bin_w in one launch).
// (2) GEMM: BK=32 ping-pong double-buffered LDS (A0/B0/A1/B1 x 8KB = same
// 32KB footprint -> occupancy stays 4 blocks/CU), ONE barrier per K-iter,
// ordered [barrier; issue gld_lds for next buf; compute cur buf] so each
// barrier's vmcnt(0) drain waits on loads that had a full compute phase
// in flight behind them (R4's back-to-back issue+drain hid nothing).
// 32x32x16 MFMA 2x2/wave, XOR-swizzled LDS (4 chunks/row, c ^ (row&3)).
// Epilogue: barrier-fenced LDS transpose -> float4 stores (R4-verified).
// ---------------------------------------------------------------------------

typedef __bf16 bf16x8 __attribute__((ext_vector_type(8)));
typedef float f32x16 __attribute__((ext_vector_type(16)));

typedef const __attribute__((address_space(1))) void* gas_ptr;
typedef __attribute__((address_space(3))) void* lds_ptr;

__device__ __forceinline__ unsigned short f2bf_rne(float f) {
    unsigned int u = __builtin_bit_cast(unsigned int, f);
    u += 0x7fffu + ((u >> 16) & 1u);   // round-to-nearest-even
    return (unsigned short)(u >> 16);
}

// Merged prep: threads [0, nx8) convert x fp32->bf16 (8 elems each);
// threads [nx8, nx8+nw8) binarize w fp32->bf16 +-1 (8 elems each).
// nx8 is a multiple of 256 so no intra-block divergence.
__global__ __launch_bounds__(256) void prep_kernel(
    const float* __restrict__ x, const float* __restrict__ w,
    unsigned short* __restrict__ xb, unsigned short* __restrict__ wb,
    int nx8, int nw8)
{
    int i = blockIdx.x * 256 + threadIdx.x;
    if (i < nx8) {
        const float4* p = reinterpret_cast<const float4*>(x + (size_t)i * 8);
        float4 f0 = p[0], f1 = p[1];
        union { unsigned short s[8]; uint4 v; } o;
        o.s[0] = f2bf_rne(f0.x); o.s[1] = f2bf_rne(f0.y);
        o.s[2] = f2bf_rne(f0.z); o.s[3] = f2bf_rne(f0.w);
        o.s[4] = f2bf_rne(f1.x); o.s[5] = f2bf_rne(f1.y);
        o.s[6] = f2bf_rne(f1.z); o.s[7] = f2bf_rne(f1.w);
        *reinterpret_cast<uint4*>(xb + (size_t)i * 8) = o.v;
    } else if (i < nx8 + nw8) {
        int j = i - nx8;
        const float4* p = reinterpret_cast<const float4*>(w + (size_t)j * 8);
        float4 f0 = p[0], f1 = p[1];
        union { unsigned short s[8]; uint4 v; } o;
        o.s[0] = (f0.x >= 0.f) ? 0x3F80u : 0xBF80u;
        o.s[1] = (f0.y >= 0.f) ? 0x3F80u : 0xBF80u;
        o.s[2] = (f0.z >= 0.f) ? 0x3F80u : 0xBF80u;
        o.s[3] = (f0.w >= 0.f) ? 0x3F80u : 0xBF80u;
        o.s[4] = (f1.x >= 0.f) ? 0x3F80u : 0xBF80u;
        o.s[5] = (f1.y >= 0.f) ? 0x3F80u : 0xBF80u;
        o.s[6] = (f1.z >= 0.f) ? 0x3F80u : 0xBF80u;
        o.s[7] = (f1.w >= 0.f) ? 0x3F80u : 0xBF80u;
        *reinterpret_cast<uint4*>(wb + (size_t)j * 8) = o.v;
    }
}

// ---------------------------------------------------------------------------
// GEMM: C[M,N] = A[M,K](bf16) * B[N,K]^T(bf16 +-1) + bias[N], fp32 out.
// 128x128 tile, BK=32, ping-pong LDS. 4 waves (2x2), each wave 64x64 via
// 2x2 of mfma_f32_32x32x16_bf16.
//
// LDS per buffer per operand: 128 rows x 32 bf16 = 8 KB, chunk = 8 bf16.
// Physical chunk of (row, kchunk c in 0..3) = row*4 + (c ^ (row&3));
// staging thread t, round j: g = j*256+t, row = g>>2, global col =
// ((g&3) ^ (row&3))*8, LDS dest = g*16B (contiguous in tid: gld_lds-legal).
//
// Operand layout 32x32x16_bf16: A[row=lane&31][k=(lane>>5)*8 + 0..7], B same
// with col=lane&31. C/D: col=lane&31, row=(reg&3)+8*(reg>>2)+4*(lane>>5).
// ---------------------------------------------------------------------------
#define TILE 128
#define BK   32

__global__ __launch_bounds__(256) void gemm_bin_kernel(
    const unsigned short* __restrict__ A,   // bf16 bits [M][K]
    const unsigned short* __restrict__ B,   // bf16 bits [N][K]
    const float* __restrict__ bias,         // [N]
    float* __restrict__ C,                  // [M][N]
    int M, int N, int K)
{
    // Layout: [A0 8K][B0 8K][A1 8K][B1 8K]
    __shared__ __align__(16) unsigned char smem[32768];

    const int tid  = threadIdx.x;
    const int lane = tid & 63;
    const int wave = tid >> 6;
    const int wm   = wave & 1;
    const int wn   = wave >> 1;
    const int bm   = blockIdx.y;   // M/128 = 64
    const int bn   = blockIdx.x;   // N/128 = 16

    const unsigned short* Agb = A + (size_t)(bm * TILE) * K;
    const unsigned short* Bgb = B + (size_t)(bn * TILE) * K;

    f32x16 acc[2][2];
#pragma unroll
    for (int a = 0; a < 2; ++a)
#pragma unroll
        for (int b = 0; b < 2; ++b)
#pragma unroll
            for (int r = 0; r < 16; ++r)
                acc[a][b][r] = 0.f;

    const int lr = lane & 31;   // row (A) / col (B) within 32-tile
    const int lk = lane >> 5;   // k-half: k = lk*8 + 0..7

    // Staging geometry: round j in {0,1}, thread t -> chunk g = j*256 + t.
    int st_row[2], st_col[2];
#pragma unroll
    for (int j = 0; j < 2; ++j) {
        int g = j * 256 + tid;
        st_row[j] = g >> 2;                           // 0..127
        st_col[j] = (((g & 3) ^ (st_row[j] & 3)) * 8);
    }

    // Stage one operand tile at k0 into LDS buffer `buf`.
    auto stage = [&](int buf, int k0) {
        unsigned short* Als = (unsigned short*)(smem + buf * 16384);
        unsigned short* Bls = (unsigned short*)(smem + buf * 16384 + 8192);
#pragma unroll
        for (int j = 0; j < 2; ++j) {
            int g = j * 256 + tid;
            __builtin_amdgcn_global_load_lds(
                (gas_ptr)(Agb + (size_t)st_row[j] * K + k0 + st_col[j]),
                (lds_ptr)&Als[g * 8], 16, 0, 0);
        }
#pragma unroll
        for (int j = 0; j < 2; ++j) {
            int g = j * 256 + tid;
            __builtin_amdgcn_global_load_lds(
                (gas_ptr)(Bgb + (size_t)st_row[j] * K + k0 + st_col[j]),
                (lds_ptr)&Bls[g * 8], 16, 0, 0);
        }
    };

    auto compute = [&](int buf) {
        const unsigned short* Als = (const unsigned short*)(smem + buf * 16384);
        const unsigned short* Bls = (const unsigned short*)(smem + buf * 16384 + 8192);
#pragma unroll
        for (int ks = 0; ks < 2; ++ks) {
            const int c = ks * 2 + lk;            // k-chunk 0..3
            bf16x8 af[2], bfv[2];
#pragma unroll
            for (int mi = 0; mi < 2; ++mi) {
                int row = wm * 64 + mi * 32 + lr;
                af[mi] = *reinterpret_cast<const bf16x8*>(
                    &Als[(row * 4 + (c ^ (lr & 3))) * 8]);
            }
#pragma unroll
            for (int ni = 0; ni < 2; ++ni) {
                int row = wn * 64 + ni * 32 + lr;
                bfv[ni] = *reinterpret_cast<const bf16x8*>(
                    &Bls[(row * 4 + (c ^ (lr & 3))) * 8]);
            }
#pragma unroll
            for (int mi = 0; mi < 2; ++mi)
#pragma unroll
                for (int ni = 0; ni < 2; ++ni)
                    acc[mi][ni] = __builtin_amdgcn_mfma_f32_32x32x16_bf16(
                        af[mi], bfv[ni], acc[mi][ni], 0, 0, 0);
        }
    };

    // Ping-pong main loop: K/BK = 64 iterations, manually unrolled x2 so the
    // buffer index is compile-time. Per iter: [barrier; issue next; compute].
    // Each barrier's vmcnt(0) drain covers loads issued BEFORE the previous
    // compute phase -> latency hidden within the wave.
    stage(0, 0);
    const int kIter = K / BK;   // 64 (even)
    for (int it = 0; it < kIter; it += 2) {
        __syncthreads();
        stage(1, (it + 1) * BK);          // it+1 < kIter always (it <= 62)
        compute(0);
        __syncthreads();
        if (it + 2 < kIter) stage(0, (it + 2) * BK);
        compute(1);
    }

    // Epilogue: per-wave private 32x64 fp32 slab (8 KB x 4 waves = 32 KB,
    // reusing staging LDS). Transpose MFMA C/D layout -> row-contiguous,
    // then float4 stores (4 rows x 256B per instruction). Barrier-fenced.
    float* eps = (float*)smem + wave * 2048;
    const int c4 = (lane & 15) * 4;   // read-phase col (floats)
    const int pr = lane >> 4;         // read-phase row-in-pass
    float4 bv = *(const float4*)&bias[bn * TILE + wn * 64 + c4];

#pragma unroll
    for (int mi = 0; mi < 2; ++mi) {
        __syncthreads();   // slab free (prior frag/epilogue reads done)
#pragma unroll
        for (int ni = 0; ni < 2; ++ni)
#pragma unroll
            for (int r = 0; r < 16; ++r) {
                int rl = (r & 3) + 8 * (r >> 2) + 4 * lk;   // 0..31
                eps[rl * 64 + ni * 32 + lr] = acc[mi][ni][r];
            }
        __syncthreads();   // transpose writes visible before reads
#pragma unroll
        for (int p = 0; p < 8; ++p) {
            int rl = p * 4 + pr;
            float4 v = *reinterpret_cast<const float4*>(&eps[rl * 64 + c4]);
            float4 o = {v.x + bv.x, v.y + bv.y, v.z + bv.z, v.w + bv.w};
            size_t grow = (size_t)(bm * TILE + wm * 64 + mi * 32 + rl);
            *reinterpret_cast<float4*>(&C[grow * N + bn * TILE + wn * 64 + c4]) = o;
        }
    }
}

extern "C" void kernel_launch(void* const* d_in, const int* in_sizes, int n_in,
                              void* d_out, int out_size, void* d_ws, size_t ws_size,
                              hipStream_t stream) {
    const float* x    = (const float*)d_in[0];   // [M, K]
    const float* w    = (const float*)d_in[1];   // [N, K]
    const float* bias = (const float*)d_in[2];   // [N]
    float* out = (float*)d_out;

    const int K = 2048;                 // IN
    const int N = in_sizes[2];          // OUT = 2048
    const int M = in_sizes[0] / K;      // 8192

    unsigned short* xb = (unsigned short*)d_ws;   // [M,K] bf16: 32 MB
    unsigned short* wb = xb + (size_t)M * K;      // [N,K] bf16 +-1: 8 MB

    const int nx8 = (M * K) / 8;        // 2M, multiple of 256
    const int nw8 = (N * K) / 8;        // 512K
    prep_kernel<<<(nx8 + nw8 + 255) / 256, 256, 0, stream>>>(x, w, xb, wb, nx8, nw8);

    dim3 grid(N / TILE, M / TILE);      // (16, 64)
    gemm_bin_kernel<<<grid, 256, 0, stream>>>(xb, wb, bias, out, M, N, K);
}

// Round 6
// 205.661 us; speedup vs baseline: 1.0059x; 1.0059x over previous
//
#include <hip/hip_runtime.h>
#include <stdint.h>

// ---------------------------------------------------------------------------
// BinaryLinear: out[M,N] = x[M,K] @ sign(W[N,K])^T + bias[N]
// M=8192, K=2048, N=2048, fp32 in/out.
// Round 6: R5's ping-pong BK=32 structure with the LDS swizzle FIXED.
// R5's swizzle c^(row&3) put 8 rows on one 4-bank quad (64B rows: quad =
// (row&1)*4 + chunk). Correct swizzle: c ^ ((row>>1)&3) -> within each
// 8-lane read phase, even rows hit quads 0-3 distinctly, odd rows 4-7
// distinctly => conflict-free (only the inherent 4 cyc/b128 remains).
// Merged prep kernel (cvt_x + bin_w in one launch, R5-verified).
// Epilogue: barrier-fenced LDS transpose -> float4 stores (R4/R5-verified).
// ---------------------------------------------------------------------------

typedef __bf16 bf16x8 __attribute__((ext_vector_type(8)));
typedef float f32x16 __attribute__((ext_vector_type(16)));

typedef const __attribute__((address_space(1))) void* gas_ptr;
typedef __attribute__((address_space(3))) void* lds_ptr;

__device__ __forceinline__ unsigned short f2bf_rne(float f) {
    unsigned int u = __builtin_bit_cast(unsigned int, f);
    u += 0x7fffu + ((u >> 16) & 1u);   // round-to-nearest-even
    return (unsigned short)(u >> 16);
}

// Merged prep: threads [0, nx8) convert x fp32->bf16 (8 elems each);
// threads [nx8, nx8+nw8) binarize w fp32->bf16 +-1 (8 elems each).
// nx8 is a multiple of 256 so no intra-block divergence.
__global__ __launch_bounds__(256) void prep_kernel(
    const float* __restrict__ x, const float* __restrict__ w,
    unsigned short* __restrict__ xb, unsigned short* __restrict__ wb,
    int nx8, int nw8)
{
    int i = blockIdx.x * 256 + threadIdx.x;
    if (i < nx8) {
        const float4* p = reinterpret_cast<const float4*>(x + (size_t)i * 8);
        float4 f0 = p[0], f1 = p[1];
        union { unsigned short s[8]; uint4 v; } o;
        o.s[0] = f2bf_rne(f0.x); o.s[1] = f2bf_rne(f0.y);
        o.s[2] = f2bf_rne(f0.z); o.s[3] = f2bf_rne(f0.w);
        o.s[4] = f2bf_rne(f1.x); o.s[5] = f2bf_rne(f1.y);
        o.s[6] = f2bf_rne(f1.z); o.s[7] = f2bf_rne(f1.w);
        *reinterpret_cast<uint4*>(xb + (size_t)i * 8) = o.v;
    } else if (i < nx8 + nw8) {
        int j = i - nx8;
        const float4* p = reinterpret_cast<const float4*>(w + (size_t)j * 8);
        float4 f0 = p[0], f1 = p[1];
        union { unsigned short s[8]; uint4 v; } o;
        o.s[0] = (f0.x >= 0.f) ? 0x3F80u : 0xBF80u;
        o.s[1] = (f0.y >= 0.f) ? 0x3F80u : 0xBF80u;
        o.s[2] = (f0.z >= 0.f) ? 0x3F80u : 0xBF80u;
        o.s[3] = (f0.w >= 0.f) ? 0x3F80u : 0xBF80u;
        o.s[4] = (f1.x >= 0.f) ? 0x3F80u : 0xBF80u;
        o.s[5] = (f1.y >= 0.f) ? 0x3F80u : 0xBF80u;
        o.s[6] = (f1.z >= 0.f) ? 0x3F80u : 0xBF80u;
        o.s[7] = (f1.w >= 0.f) ? 0x3F80u : 0xBF80u;
        *reinterpret_cast<uint4*>(wb + (size_t)j * 8) = o.v;
    }
}

// ---------------------------------------------------------------------------
// GEMM: C[M,N] = A[M,K](bf16) * B[N,K]^T(bf16 +-1) + bias[N], fp32 out.
// 128x128 tile, BK=32, ping-pong LDS (A0/B0/A1/B1 x 8KB = 32KB). 4 waves
// (2x2), each wave 64x64 via 2x2 of mfma_f32_32x32x16_bf16. One barrier
// per K-iter: [barrier; issue next-buf loads; compute cur buf] so each
// barrier's vmcnt(0) drain covers loads with a full compute phase behind.
//
// LDS swizzle (per 8KB buffer: 128 rows x 32 bf16 = 64B rows, chunk=16B):
// physical chunk of (row, c in 0..3) = row*4 + (c ^ ((row>>1)&3)).
// Bank-quad = (row&1)*4 + (c^swz): 8-lane phases hit 8 distinct quads.
// Staging thread t, round j: g=j*256+t, row=g>>2, global col =
// ((g&3) ^ ((row>>1)&3))*8; LDS dest = g*16B (contiguous: gld_lds-legal;
// 4 threads/row permute chunks within one 64B segment -> coalescing kept).
//
// Operand layout 32x32x16_bf16: A[row=lane&31][k=(lane>>5)*8 + 0..7], B same
// with col=lane&31. C/D: col=lane&31, row=(reg&3)+8*(reg>>2)+4*(lane>>5).
// ---------------------------------------------------------------------------
#define TILE 128
#define BK   32

__global__ __launch_bounds__(256) void gemm_bin_kernel(
    const unsigned short* __restrict__ A,   // bf16 bits [M][K]
    const unsigned short* __restrict__ B,   // bf16 bits [N][K]
    const float* __restrict__ bias,         // [N]
    float* __restrict__ C,                  // [M][N]
    int M, int N, int K)
{
    // Layout: [A0 8K][B0 8K][A1 8K][B1 8K]
    __shared__ __align__(16) unsigned char smem[32768];

    const int tid  = threadIdx.x;
    const int lane = tid & 63;
    const int wave = tid >> 6;
    const int wm   = wave & 1;
    const int wn   = wave >> 1;
    const int bm   = blockIdx.y;   // M/128 = 64
    const int bn   = blockIdx.x;   // N/128 = 16

    const unsigned short* Agb = A + (size_t)(bm * TILE) * K;
    const unsigned short* Bgb = B + (size_t)(bn * TILE) * K;

    f32x16 acc[2][2];
#pragma unroll
    for (int a = 0; a < 2; ++a)
#pragma unroll
        for (int b = 0; b < 2; ++b)
#pragma unroll
            for (int r = 0; r < 16; ++r)
                acc[a][b][r] = 0.f;

    const int lr = lane & 31;       // row (A) / col (B) within 32-tile
    const int lk = lane >> 5;       // k-half: k = lk*8 + 0..7
    const int swzl = (lr >> 1) & 3; // read-side swizzle (tile-row offsets are
                                    // multiples of 32 -> (row>>1)&3 == (lr>>1)&3)

    // Staging geometry: round j in {0,1}, thread t -> chunk g = j*256 + t.
    int st_row[2], st_col[2];
#pragma unroll
    for (int j = 0; j < 2; ++j) {
        int g = j * 256 + tid;
        st_row[j] = g >> 2;                                   // 0..127
        st_col[j] = (((g & 3) ^ ((st_row[j] >> 1) & 3)) * 8); // swizzled col
    }

    // Stage one (A,B) tile pair at k0 into LDS buffer `buf`.
    auto stage = [&](int buf, int k0) {
        unsigned short* Als = (unsigned short*)(smem + buf * 16384);
        unsigned short* Bls = (unsigned short*)(smem + buf * 16384 + 8192);
#pragma unroll
        for (int j = 0; j < 2; ++j) {
            int g = j * 256 + tid;
            __builtin_amdgcn_global_load_lds(
                (gas_ptr)(Agb + (size_t)st_row[j] * K + k0 + st_col[j]),
                (lds_ptr)&Als[g * 8], 16, 0, 0);
        }
#pragma unroll
        for (int j = 0; j < 2; ++j) {
            int g = j * 256 + tid;
            __builtin_amdgcn_global_load_lds(
                (gas_ptr)(Bgb + (size_t)st_row[j] * K + k0 + st_col[j]),
                (lds_ptr)&Bls[g * 8], 16, 0, 0);
        }
    };

    auto compute = [&](int buf) {
        const unsigned short* Als = (const unsigned short*)(smem + buf * 16384);
        const unsigned short* Bls = (const unsigned short*)(smem + buf * 16384 + 8192);
#pragma unroll
        for (int ks = 0; ks < 2; ++ks) {
            const int c = ks * 2 + lk;            // k-chunk 0..3
            bf16x8 af[2], bfv[2];
#pragma unroll
            for (int mi = 0; mi < 2; ++mi) {
                int row = wm * 64 + mi * 32 + lr;
                af[mi] = *reinterpret_cast<const bf16x8*>(
                    &Als[(row * 4 + (c ^ swzl)) * 8]);
            }
#pragma unroll
            for (int ni = 0; ni < 2; ++ni) {
                int row = wn * 64 + ni * 32 + lr;
                bfv[ni] = *reinterpret_cast<const bf16x8*>(
                    &Bls[(row * 4 + (c ^ swzl)) * 8]);
            }
#pragma unroll
            for (int mi = 0; mi < 2; ++mi)
#pragma unroll
                for (int ni = 0; ni < 2; ++ni)
                    acc[mi][ni] = __builtin_amdgcn_mfma_f32_32x32x16_bf16(
                        af[mi], bfv[ni], acc[mi][ni], 0, 0, 0);
        }
    };

    // Ping-pong main loop: K/BK = 64 iterations, unrolled x2 so the buffer
    // index is compile-time. Per iter: [barrier; issue next; compute cur].
    stage(0, 0);
    const int kIter = K / BK;   // 64 (even)
    for (int it = 0; it < kIter; it += 2) {
        __syncthreads();
        stage(1, (it + 1) * BK);          // it+1 < kIter always (it <= 62)
        compute(0);
        __syncthreads();
        if (it + 2 < kIter) stage(0, (it + 2) * BK);
        compute(1);
    }

    // Epilogue: per-wave private 32x64 fp32 slab (8 KB x 4 waves = 32 KB,
    // reusing staging LDS). Transpose MFMA C/D layout -> row-contiguous,
    // then float4 stores (4 rows x 256B per instruction). Barrier-fenced.
    float* eps = (float*)smem + wave * 2048;
    const int c4 = (lane & 15) * 4;   // read-phase col (floats)
    const int pr = lane >> 4;         // read-phase row-in-pass
    float4 bv = *(const float4*)&bias[bn * TILE + wn * 64 + c4];

#pragma unroll
    for (int mi = 0; mi < 2; ++mi) {
        __syncthreads();   // slab free (prior frag/epilogue reads done)
#pragma unroll
        for (int ni = 0; ni < 2; ++ni)
#pragma unroll
            for (int r = 0; r < 16; ++r) {
                int rl = (r & 3) + 8 * (r >> 2) + 4 * lk;   // 0..31
                eps[rl * 64 + ni * 32 + lr] = acc[mi][ni][r];
            }
        __syncthreads();   // transpose writes visible before reads
#pragma unroll
        for (int p = 0; p < 8; ++p) {
            int rl = p * 4 + pr;
            float4 v = *reinterpret_cast<const float4*>(&eps[rl * 64 + c4]);
            float4 o = {v.x + bv.x, v.y + bv.y, v.z + bv.z, v.w + bv.w};
            size_t grow = (size_t)(bm * TILE + wm * 64 + mi * 32 + rl);
            *reinterpret_cast<float4*>(&C[grow * N + bn * TILE + wn * 64 + c4]) = o;
        }
    }
}

extern "C" void kernel_launch(void* const* d_in, const int* in_sizes, int n_in,
                              void* d_out, int out_size, void* d_ws, size_t ws_size,
                              hipStream_t stream) {
    const float* x    = (const float*)d_in[0];   // [M, K]
    const float* w    = (const float*)d_in[1];   // [N, K]
    const float* bias = (const float*)d_in[2];   // [N]
    float* out = (float*)d_out;

    const int K = 2048;                 // IN
    const int N = in_sizes[2];          // OUT = 2048
    const int M = in_sizes[0] / K;      // 8192

    unsigned short* xb = (unsigned short*)d_ws;   // [M,K] bf16: 32 MB
    unsigned short* wb = xb + (size_t)M * K;      // [N,K] bf16 +-1: 8 MB

    const int nx8 = (M * K) / 8;        // 2M, multiple of 256
    const int nw8 = (N * K) / 8;        // 512K
    prep_kernel<<<(nx8 + nw8 + 255) / 256, 256, 0, stream>>>(x, w, xb, wb, nx8, nw8);

    dim3 grid(N / TILE, M / TILE);      // (16, 64)
    gemm_bin_kernel<<<grid, 256, 0, stream>>>(xb, wb, bias, out, M, N, K);
}